// Round 8
// baseline (25.596 us; speedup 1.0000x reference)
//
#include <hip/hip_runtime.h>
#include <stdint.h>

#define BB 16
#define CI 64
#define CO 64
#define HH 32
#define WW 32

// full adder / half adder on 32-lane bitsets
__device__ __forceinline__ void fadd(uint32_t a, uint32_t b, uint32_t c,
                                     uint32_t& s, uint32_t& cy) {
    uint32_t t = a ^ b;
    s = t ^ c;
    cy = (t & c) | (a & b);
}
__device__ __forceinline__ void hadd(uint32_t a, uint32_t b, uint32_t& s, uint32_t& cy) {
    s = a ^ b;
    cy = a & b;
}
__device__ __forceinline__ void add5(const uint32_t* a, const uint32_t* b, uint32_t* r) {
    uint32_t c;
    hadd(a[0], b[0], r[0], c);
#pragma unroll
    for (int k = 1; k < 5; ++k) fadd(a[k], b[k], c, r[k], c);
    r[5] = c;
}
__device__ __forceinline__ void add6(const uint32_t* a, const uint32_t* b, uint32_t* r) {
    uint32_t c;
    hadd(a[0], b[0], r[0], c);
#pragma unroll
    for (int k = 1; k < 6; ++k) fadd(a[k], b[k], c, r[k], c);
    r[6] = c;
}

// ONE dispatch. blocks 0..511: (b,y) SWAR interior (y=0/31 exit immediately);
// blocks 512..639: y-border rows via generic-LUT path. All blocks self-pack
// weights and x-rows from the raw floats (w is L2-resident; x rows coalesced).
__global__ __launch_bounds__(256) void fused_kernel(const float* __restrict__ x,
                                                    const float* __restrict__ w,
                                                    float* __restrict__ out) {
    __shared__ uint32_t wlds[CI * CO];       // 16 KiB (border path uses first 1024)
    __shared__ uint4 xr4[CI];                // rows y-1,y,y+1 per ci
    __shared__ uint32_t red[4][CO][5];       // per-ciq 5 bit-planes
    __shared__ uint32_t planes7[CO][7];      // reduced 7 bit-planes
    __shared__ int bord[CO][2][2];           // x-border partial sums

    const int bid = blockIdx.x;
    const int tid = threadIdx.x;

    if (bid < BB * HH) {
        const int b = bid >> 5, y = bid & 31;
        if (y == 0 || y == HH - 1) return;   // uniform exit before any barrier

        // ---- pack weights from floats: 4 ci-quads per thread, float4 over ci
        for (int q = tid; q < (CI / 4) * CO; q += 256) {
            int co = q >> 4;
            int ci0 = (q & 15) * 4;
            uint32_t b0 = 0, b1 = 0, b2 = 0, b3 = 0;
#pragma unroll
            for (int t = 0; t < 9; ++t) {
                const float4 v = *(const float4*)&w[(co * 9 + t) * CI + ci0];
                b0 |= (v.x > 0.f ? 1u : 0u) << t;
                b1 |= (v.y > 0.f ? 1u : 0u) << t;
                b2 |= (v.z > 0.f ? 1u : 0u) << t;
                b3 |= (v.w > 0.f ? 1u : 0u) << t;
            }
            wlds[(ci0 + 0) * CO + co] = b0 ^ 0x1FFu;   // inverted: match = xn ^ winv
            wlds[(ci0 + 1) * CO + co] = b1 ^ 0x1FFu;
            wlds[(ci0 + 2) * CO + co] = b2 ^ 0x1FFu;
            wlds[(ci0 + 3) * CO + co] = b3 ^ 0x1FFu;
        }
        // ---- pack 3 x-rows via ballot (192 tasks, 2 half-wave tasks/iter/wave)
        {
            const int wave = tid >> 6;
            const int lane = tid & 63;
            const int half = lane >> 5;
            const int px = lane & 31;
#pragma unroll
            for (int j = 0; j < 24; ++j) {
                int task = wave * 48 + j * 2 + half;
                int r = task >> 6;           // 0..2
                int ci = task & 63;
                float v = x[((b * CI + ci) * HH + (y - 1 + r)) * WW + px];  // y interior
                unsigned long long mask = __ballot(v > 0.f);
                if (px == 0)
                    ((uint32_t*)&xr4[ci])[r] = (uint32_t)(half ? (mask >> 32) : mask);
            }
        }
        __syncthreads();

        const int co = tid & 63, ciq = tid >> 6;

        // ---- SWAR majority-of-9 over 32 pixels, 16 ci per thread ----
        uint32_t maj[16];
#pragma unroll
        for (int i = 0; i < 16; ++i) {
            const int ci = ciq * 16 + i;
            const uint4 xr = xr4[ci];
            const uint32_t wn = wlds[ci * CO + co];
            const uint32_t T0 = xr.x << 1, T1 = xr.x, T2 = xr.x >> 1;
            const uint32_t T3 = xr.y << 1, T4 = xr.y, T5 = xr.y >> 1;
            const uint32_t T6 = xr.z << 1, T7 = xr.z, T8 = xr.z >> 1;
            const uint32_t m0 = T0 ^ (uint32_t)(-(int)((wn >> 0) & 1));
            const uint32_t m1 = T1 ^ (uint32_t)(-(int)((wn >> 1) & 1));
            const uint32_t m2 = T2 ^ (uint32_t)(-(int)((wn >> 2) & 1));
            const uint32_t m3 = T3 ^ (uint32_t)(-(int)((wn >> 3) & 1));
            const uint32_t m4 = T4 ^ (uint32_t)(-(int)((wn >> 4) & 1));
            const uint32_t m5 = T5 ^ (uint32_t)(-(int)((wn >> 5) & 1));
            const uint32_t m6 = T6 ^ (uint32_t)(-(int)((wn >> 6) & 1));
            const uint32_t m7 = T7 ^ (uint32_t)(-(int)((wn >> 7) & 1));
            const uint32_t m8 = T8 ^ (uint32_t)(-(int)((wn >> 8) & 1));
            uint32_t s1, c1, s2, c2, s3, c3, S, C, D, E;
            fadd(m0, m1, m2, s1, c1);
            fadd(m3, m4, m5, s2, c2);
            fadd(m6, m7, m8, s3, c3);
            fadd(s1, s2, s3, S, C);              // m = S + 2C + 2D + 4E
            fadd(c1, c2, c3, D, E);
            maj[i] = (E & (S | C | D)) | (~E & (S & C & D));   // m >= 5
        }

        // ---- CSA: 16 maj bits -> 5 planes ----
        uint32_t A[5], Bw[5];
        fadd(maj[0], maj[1], maj[2], A[0], Bw[0]);
        fadd(maj[3], maj[4], maj[5], A[1], Bw[1]);
        fadd(maj[6], maj[7], maj[8], A[2], Bw[2]);
        fadd(maj[9], maj[10], maj[11], A[3], Bw[3]);
        fadd(maj[12], maj[13], maj[14], A[4], Bw[4]);
        uint32_t u1, v1, u2, v2, p0, v3;
        fadd(A[0], A[1], A[2], u1, v1);
        fadd(A[3], A[4], maj[15], u2, v2);
        hadd(u1, u2, p0, v3);
        uint32_t e1, f1, e2, f2, e3, f3, p1, f4;
        fadd(Bw[0], Bw[1], Bw[2], e1, f1);
        fadd(Bw[3], Bw[4], v1, e2, f2);
        fadd(e1, e2, v2, e3, f3);
        hadd(e3, v3, p1, f4);
        uint32_t g1, h1, p2, h2, p3, p4;
        fadd(f1, f2, f3, g1, h1);
        hadd(g1, f4, p2, h2);
        hadd(h1, h2, p3, p4);
        red[ciq][co][0] = p0; red[ciq][co][1] = p1; red[ciq][co][2] = p2;
        red[ciq][co][3] = p3; red[ciq][co][4] = p4;

        // ---- x-border scalar fixup: px 0 and 31 (N=6), 32 ci per thread ----
        {
            const int fco = tid & 63, side = (tid >> 6) & 1, cih = tid >> 7;
            const int px = side * (WW - 1);
            const uint32_t rowm = (px > 0 ? 1u : 0u) | 2u | (px < WW - 1 ? 4u : 0u);
            const uint32_t vmask = rowm | (rowm << 3) | (rowm << 6);
            const uint32_t N = __popc(vmask);
            const uint32_t nt1 = N >> 1, nt2 = (N - 1) >> 1;
            uint32_t lut = 0;
            for (uint32_t m = 1; m <= 9; ++m)
                lut |= (uint32_t)((m > nt1) + (m > nt2)) << (2 * m);
            int acc = 0;
            for (int i = 0; i < 32; ++i) {
                const int ci = cih * 32 + i;
                const uint4 xr = xr4[ci];
                const uint32_t wn = wlds[ci * CO + fco];
                const uint32_t n0 = (uint32_t)((((uint64_t)xr.x) << 1) >> px) & 7u;
                const uint32_t n1 = (uint32_t)((((uint64_t)xr.y) << 1) >> px) & 7u;
                const uint32_t n2 = (uint32_t)((((uint64_t)xr.z) << 1) >> px) & 7u;
                const uint32_t xn = n0 | (n1 << 3) | (n2 << 6);
                const uint32_t mm = (uint32_t)__popc((xn ^ wn) & vmask);
                acc += (lut >> (2 * mm)) & 3u;
            }
            bord[fco][side][cih] = acc;
        }
        __syncthreads();

        // ---- reduce 4 ciq counts -> 7 planes (wave 0) ----
        if (tid < 64) {
            uint32_t x0[6], x1[6], rr[7];
            add5(red[0][tid], red[1][tid], x0);
            add5(red[2][tid], red[3][tid], x1);
            add6(x0, x1, rr);
#pragma unroll
            for (int k = 0; k < 7; ++k) planes7[tid][k] = rr[k];
        }
        __syncthreads();

        // ---- extract + store ----
        {
            const int oco = tid & 63, q = tid >> 6;
            uint32_t pl[7];
#pragma unroll
            for (int k = 0; k < 7; ++k) pl[k] = planes7[oco][k];
            float vals[8];
#pragma unroll
            for (int j = 0; j < 8; ++j) {
                const int px = q * 8 + j;
                uint32_t cnt = 0;
#pragma unroll
                for (int k = 0; k < 7; ++k) cnt += ((pl[k] >> px) & 1u) << k;
                vals[j] = (float)(2 * (int)cnt - CI);
            }
            if (q == 0) vals[0] = (float)(bord[oco][0][0] + bord[oco][0][1] - CI);
            if (q == 3) vals[7] = (float)(bord[oco][1][0] + bord[oco][1][1] - CI);
            float4* op = (float4*)&out[((size_t)(b * CO + oco) * HH + y) * WW + q * 8];
            op[0] = make_float4(vals[0], vals[1], vals[2], vals[3]);
            op[1] = make_float4(vals[4], vals[5], vals[6], vals[7]);
        }
    } else {
        // ---- y-border rows (y=0,31): generic-LUT, block = (b, yb, co-quarter) ----
        const int idx = bid - BB * HH;            // 0..127
        const int b = idx >> 3, yb = (idx >> 2) & 1, coq = idx & 3;
        const int y = yb * (HH - 1);
        // pack winv subset [64 ci][16 co] from floats: 4 entries per thread
        for (int e = tid; e < CI * 16; e += 256) {
            int ci = e >> 4, c = e & 15;
            int co = coq * 16 + c;
            uint32_t bits = 0;
#pragma unroll
            for (int t = 0; t < 9; ++t)
                bits |= (w[(co * 9 + t) * CI + ci] > 0.f ? 1u : 0u) << t;
            wlds[e] = bits ^ 0x1FFu;
        }
        // pack 3 x-rows (OOB row -> 0)
        {
            const int wave = tid >> 6;
            const int lane = tid & 63;
            const int half = lane >> 5;
            const int px = lane & 31;
#pragma unroll
            for (int j = 0; j < 24; ++j) {
                int task = wave * 48 + j * 2 + half;
                int r = task >> 6;
                int ci = task & 63;
                int yy = y - 1 + r;
                float v = (yy >= 0 && yy < HH) ? x[((b * CI + ci) * HH + yy) * WW + px] : 0.f;
                unsigned long long mask = __ballot(v > 0.f);
                if (px == 0)
                    ((uint32_t*)&xr4[ci])[r] = (uint32_t)(half ? (mask >> 32) : mask);
            }
        }
        __syncthreads();

        const int px = tid & 31, cog = tid >> 5;   // 2 co each
        const uint32_t rowm = (px > 0 ? 1u : 0u) | 2u | (px < WW - 1 ? 4u : 0u);
        const uint32_t vmask = (y > 0 ? rowm : 0u) | (rowm << 3) |
                               (y < HH - 1 ? (rowm << 6) : 0u);
        const uint32_t N = __popc(vmask);
        const uint32_t nt1 = N >> 1, nt2 = (N - 1) >> 1;
        uint32_t lut = 0;
        for (uint32_t m = 1; m <= 9; ++m)
            lut |= (uint32_t)((m > nt1) + (m > nt2)) << (2 * m);
        int a0 = 0, a1 = 0;
        for (int ci = 0; ci < CI; ++ci) {
            const uint4 xr = xr4[ci];
            const uint32_t n0 = (uint32_t)((((uint64_t)xr.x) << 1) >> px) & 7u;
            const uint32_t n1 = (uint32_t)((((uint64_t)xr.y) << 1) >> px) & 7u;
            const uint32_t n2 = (uint32_t)((((uint64_t)xr.z) << 1) >> px) & 7u;
            const uint32_t xn = n0 | (n1 << 3) | (n2 << 6);
            const uint32_t w0 = wlds[ci * 16 + cog * 2 + 0];
            const uint32_t w1 = wlds[ci * 16 + cog * 2 + 1];
            uint32_t mm;
            mm = (uint32_t)__popc((xn ^ w0) & vmask); a0 += (lut >> (2 * mm)) & 3u;
            mm = (uint32_t)__popc((xn ^ w1) & vmask); a1 += (lut >> (2 * mm)) & 3u;
        }
        const int co0 = coq * 16 + cog * 2;
        out[((size_t)(b * CO + co0 + 0) * HH + y) * WW + px] = (float)(a0 - CI);
        out[((size_t)(b * CO + co0 + 1) * HH + y) * WW + px] = (float)(a1 - CI);
    }
}

extern "C" void kernel_launch(void* const* d_in, const int* in_sizes, int n_in,
                              void* d_out, int out_size, void* d_ws, size_t ws_size,
                              hipStream_t stream) {
    const float* x = (const float*)d_in[0];
    const float* w = (const float*)d_in[1];
    float* out = (float*)d_out;

    fused_kernel<<<BB * HH + 128, 256, 0, stream>>>(x, w, out);
}

// Round 9
// 21.349 us; speedup vs baseline: 1.1989x; 1.1989x over previous
//
#include <hip/hip_runtime.h>
#include <stdint.h>

#define BB 16
#define CI 64
#define CO 64
#define HH 32
#define WW 32

// full adder / half adder on 32-lane bitsets
__device__ __forceinline__ void fadd(uint32_t a, uint32_t b, uint32_t c,
                                     uint32_t& s, uint32_t& cy) {
    uint32_t t = a ^ b;
    s = t ^ c;
    cy = (t & c) | (a & b);
}
__device__ __forceinline__ void hadd(uint32_t a, uint32_t b, uint32_t& s, uint32_t& cy) {
    s = a ^ b;
    cy = a & b;
}
__device__ __forceinline__ void add5(const uint32_t* a, const uint32_t* b, uint32_t* r) {
    uint32_t c;
    hadd(a[0], b[0], r[0], c);
#pragma unroll
    for (int k = 1; k < 5; ++k) fadd(a[k], b[k], c, r[k], c);
    r[5] = c;
}
__device__ __forceinline__ void add6(const uint32_t* a, const uint32_t* b, uint32_t* r) {
    uint32_t c;
    hadd(a[0], b[0], r[0], c);
#pragma unroll
    for (int k = 1; k < 6; ++k) fadd(a[k], b[k], c, r[k], c);
    r[6] = c;
}

// ---- dispatch 1: pack x row-bitmasks (512 grid-stride blocks) + winv (16 blocks)
__global__ __launch_bounds__(256) void pack_kernel(const float* __restrict__ x,
                                                   const float* __restrict__ w,
                                                   uint32_t* __restrict__ xbits,
                                                   uint32_t* __restrict__ winv) {
    const int bid = blockIdx.x;
    const int tid = threadIdx.x;
    if (bid < 512) {
        const int base = bid * 2048;
#pragma unroll
        for (int it = 0; it < 8; ++it) {
            int p = base + it * 256 + tid;
            unsigned long long mask = __ballot(x[p] > 0.0f);
            int lane = tid & 63;
            if ((lane & 31) == 0)
                xbits[p >> 5] = (lane & 32) ? (uint32_t)(mask >> 32) : (uint32_t)mask;
        }
    } else {
        int idx = (bid - 512) * 256 + tid;         // 0..4095
        int ci = idx & 63, co = idx >> 6;          // coalesced over ci
        uint32_t bits = 0;
#pragma unroll
        for (int t = 0; t < 9; ++t)
            bits |= (w[(co * 9 + t) * CI + ci] > 0.f ? 1u : 0u) << t;
        winv[ci * CO + co] = bits ^ 0x1FFu;        // [ci][co], inverted
    }
}

// ---- dispatch 2: blocks 0..511 = (b,y) SWAR interior; 512..639 = y-border rows.
__global__ __launch_bounds__(256) void core_kernel(const uint32_t* __restrict__ xbits,
                                                   const uint32_t* __restrict__ winv,
                                                   float* __restrict__ out) {
    __shared__ uint32_t wlds[CI * CO];       // 16 KiB
    __shared__ uint4 xr4[CI];                // rows y-1,y,y+1 per ci
    __shared__ uint32_t xnb[2][CI];          // 9-bit border windows (px=0 / px=31)
    __shared__ uint32_t red[4][CO][5];       // per-ciq 5 bit-planes
    __shared__ uint32_t planes7[CO][7];      // reduced 7 bit-planes
    __shared__ int bord[CO][2][2];           // x-border partial sums

    const int bid = blockIdx.x;
    const int tid = threadIdx.x;

    if (bid < BB * HH) {
        const int b = bid >> 5, y = bid & 31;
        if (y == 0 || y == HH - 1) return;   // uniform exit before any barrier

        {   // stage winv (coalesced)
            const uint4* src = (const uint4*)winv;
            uint4* dst = (uint4*)wlds;
#pragma unroll
            for (int i = 0; i < 4; ++i) dst[tid + i * 256] = src[tid + i * 256];
        }
        // stage 3 x-rows (192 tasks) + border windows (128 tasks)
        for (int i = tid; i < 192 + 128; i += 256) {
            if (i < 192) {
                int r = i >> 6, ci = i & 63;
                ((uint32_t*)&xr4[ci])[r] = xbits[(b * CI + ci) * HH + (y - 1 + r)];
            } else {
                int k = i - 192;
                int side = k >> 6, ci = k & 63;
                const uint32_t* rp = &xbits[(b * CI + ci) * HH + (y - 1)];
                uint32_t r0 = rp[0], r1 = rp[1], r2 = rp[2];
                uint32_t n0, n1, n2;
                if (side == 0) {             // px=0: taps dx=-1 zeroed
                    n0 = (r0 & 3u) << 1; n1 = (r1 & 3u) << 1; n2 = (r2 & 3u) << 1;
                } else {                     // px=31: taps dx=+1 zeroed
                    n0 = (r0 >> 30) & 3u; n1 = (r1 >> 30) & 3u; n2 = (r2 >> 30) & 3u;
                }
                xnb[side][ci] = n0 | (n1 << 3) | (n2 << 6);
            }
        }
        __syncthreads();

        const int co = tid & 63, ciq = tid >> 6;

        // ---- SWAR majority-of-9 over 32 pixels, 16 ci per thread ----
        uint32_t maj[16];
#pragma unroll
        for (int i = 0; i < 16; ++i) {
            const int ci = ciq * 16 + i;
            const uint4 xr = xr4[ci];
            const uint32_t wn = wlds[ci * CO + co];
            const uint32_t T0 = xr.x << 1, T1 = xr.x, T2 = xr.x >> 1;
            const uint32_t T3 = xr.y << 1, T4 = xr.y, T5 = xr.y >> 1;
            const uint32_t T6 = xr.z << 1, T7 = xr.z, T8 = xr.z >> 1;
            const uint32_t m0 = T0 ^ (uint32_t)(-(int)((wn >> 0) & 1));
            const uint32_t m1 = T1 ^ (uint32_t)(-(int)((wn >> 1) & 1));
            const uint32_t m2 = T2 ^ (uint32_t)(-(int)((wn >> 2) & 1));
            const uint32_t m3 = T3 ^ (uint32_t)(-(int)((wn >> 3) & 1));
            const uint32_t m4 = T4 ^ (uint32_t)(-(int)((wn >> 4) & 1));
            const uint32_t m5 = T5 ^ (uint32_t)(-(int)((wn >> 5) & 1));
            const uint32_t m6 = T6 ^ (uint32_t)(-(int)((wn >> 6) & 1));
            const uint32_t m7 = T7 ^ (uint32_t)(-(int)((wn >> 7) & 1));
            const uint32_t m8 = T8 ^ (uint32_t)(-(int)((wn >> 8) & 1));
            uint32_t s1, c1, s2, c2, s3, c3, S, C, D, E;
            fadd(m0, m1, m2, s1, c1);
            fadd(m3, m4, m5, s2, c2);
            fadd(m6, m7, m8, s3, c3);
            fadd(s1, s2, s3, S, C);              // m = S + 2C + 2D + 4E
            fadd(c1, c2, c3, D, E);
            maj[i] = (E & (S | C | D)) | (~E & (S & C & D));   // m >= 5
        }

        // ---- CSA: 16 maj bits -> 5 planes ----
        uint32_t A[5], Bw[5];
        fadd(maj[0], maj[1], maj[2], A[0], Bw[0]);
        fadd(maj[3], maj[4], maj[5], A[1], Bw[1]);
        fadd(maj[6], maj[7], maj[8], A[2], Bw[2]);
        fadd(maj[9], maj[10], maj[11], A[3], Bw[3]);
        fadd(maj[12], maj[13], maj[14], A[4], Bw[4]);
        uint32_t u1, v1, u2, v2, p0, v3;
        fadd(A[0], A[1], A[2], u1, v1);
        fadd(A[3], A[4], maj[15], u2, v2);
        hadd(u1, u2, p0, v3);
        uint32_t e1, f1, e2, f2, e3, f3, p1, f4;
        fadd(Bw[0], Bw[1], Bw[2], e1, f1);
        fadd(Bw[3], Bw[4], v1, e2, f2);
        fadd(e1, e2, v2, e3, f3);
        hadd(e3, v3, p1, f4);
        uint32_t g1, h1, p2, h2, p3, p4;
        fadd(f1, f2, f3, g1, h1);
        hadd(g1, f4, p2, h2);
        hadd(h1, h2, p3, p4);
        red[ciq][co][0] = p0; red[ciq][co][1] = p1; red[ciq][co][2] = p2;
        red[ciq][co][3] = p3; red[ciq][co][4] = p4;

        // ---- x-border fixup from precomputed windows: N=6, lut const ----
        {
            const int fco = tid & 63, side = (tid >> 6) & 1, cih = tid >> 7;
            const uint32_t vmask = side ? 0x0DBu : 0x1B6u;
            const uint32_t lut = 0xAAA40u;       // (m>3)+(m>2) at 2-bit slot 2m
            int acc = 0;
#pragma unroll 4
            for (int i = 0; i < 32; ++i) {
                const int ci = cih * 32 + i;
                const uint32_t xn = xnb[side][ci];
                const uint32_t wn = wlds[ci * CO + fco];
                const uint32_t mm = (uint32_t)__popc((xn ^ wn) & vmask);
                acc += (lut >> (2 * mm)) & 3u;
            }
            bord[fco][side][cih] = acc;
        }
        __syncthreads();

        // ---- reduce 4 ciq counts -> 7 planes (wave 0) ----
        if (tid < 64) {
            uint32_t x0[6], x1[6], rr[7];
            add5(red[0][tid], red[1][tid], x0);
            add5(red[2][tid], red[3][tid], x1);
            add6(x0, x1, rr);
#pragma unroll
            for (int k = 0; k < 7; ++k) planes7[tid][k] = rr[k];
        }
        __syncthreads();

        // ---- extract + store ----
        {
            const int oco = tid & 63, q = tid >> 6;
            uint32_t pl[7];
#pragma unroll
            for (int k = 0; k < 7; ++k) pl[k] = planes7[oco][k];
            float vals[8];
#pragma unroll
            for (int j = 0; j < 8; ++j) {
                const int px = q * 8 + j;
                uint32_t cnt = 0;
#pragma unroll
                for (int k = 0; k < 7; ++k) cnt += ((pl[k] >> px) & 1u) << k;
                vals[j] = (float)(2 * (int)cnt - CI);
            }
            if (q == 0) vals[0] = (float)(bord[oco][0][0] + bord[oco][0][1] - CI);
            if (q == 3) vals[7] = (float)(bord[oco][1][0] + bord[oco][1][1] - CI);
            float4* op = (float4*)&out[((size_t)(b * CO + oco) * HH + y) * WW + q * 8];
            op[0] = make_float4(vals[0], vals[1], vals[2], vals[3]);
            op[1] = make_float4(vals[4], vals[5], vals[6], vals[7]);
        }
    } else {
        // ---- y-border rows (y=0,31): generic-LUT, block = (b, yb, co-quarter) ----
        const int idx = bid - BB * HH;            // 0..127
        const int b = idx >> 3, yb = (idx >> 2) & 1, coq = idx & 3;
        const int y = yb * (HH - 1);
        for (int i = tid; i < CI * 16; i += 256) {  // winv subset [ci][16 co]
            int ci = i >> 4, c = i & 15;
            wlds[i] = winv[ci * CO + coq * 16 + c];
        }
        if (tid < 3 * CI) {
            int r = tid >> 6, ci = tid & 63;
            int yy = y - 1 + r;
            ((uint32_t*)&xr4[ci])[r] = (yy >= 0 && yy < HH) ? xbits[(b * CI + ci) * HH + yy] : 0u;
        }
        __syncthreads();

        const int px = tid & 31, cog = tid >> 5;   // 2 co each
        const uint32_t rowm = (px > 0 ? 1u : 0u) | 2u | (px < WW - 1 ? 4u : 0u);
        const uint32_t vmask = (y > 0 ? rowm : 0u) | (rowm << 3) |
                               (y < HH - 1 ? (rowm << 6) : 0u);
        const uint32_t N = __popc(vmask);
        const uint32_t nt1 = N >> 1, nt2 = (N - 1) >> 1;
        uint32_t lut = 0;
        for (uint32_t m = 1; m <= 9; ++m)
            lut |= (uint32_t)((m > nt1) + (m > nt2)) << (2 * m);
        int a0 = 0, a1 = 0;
        for (int ci = 0; ci < CI; ++ci) {
            const uint4 xr = xr4[ci];
            const uint32_t n0 = (uint32_t)((((uint64_t)xr.x) << 1) >> px) & 7u;
            const uint32_t n1 = (uint32_t)((((uint64_t)xr.y) << 1) >> px) & 7u;
            const uint32_t n2 = (uint32_t)((((uint64_t)xr.z) << 1) >> px) & 7u;
            const uint32_t xn = n0 | (n1 << 3) | (n2 << 6);
            const uint32_t w0 = wlds[ci * 16 + cog * 2 + 0];
            const uint32_t w1 = wlds[ci * 16 + cog * 2 + 1];
            uint32_t mm;
            mm = (uint32_t)__popc((xn ^ w0) & vmask); a0 += (lut >> (2 * mm)) & 3u;
            mm = (uint32_t)__popc((xn ^ w1) & vmask); a1 += (lut >> (2 * mm)) & 3u;
        }
        const int co0 = coq * 16 + cog * 2;
        out[((size_t)(b * CO + co0 + 0) * HH + y) * WW + px] = (float)(a0 - CI);
        out[((size_t)(b * CO + co0 + 1) * HH + y) * WW + px] = (float)(a1 - CI);
    }
}

extern "C" void kernel_launch(void* const* d_in, const int* in_sizes, int n_in,
                              void* d_out, int out_size, void* d_ws, size_t ws_size,
                              hipStream_t stream) {
    const float* x = (const float*)d_in[0];
    const float* w = (const float*)d_in[1];
    float* out = (float*)d_out;

    uint32_t* xbits = (uint32_t*)d_ws;          // 16384 words
    uint32_t* winv = xbits + BB * CI * HH;      // 4096 words

    pack_kernel<<<512 + 16, 256, 0, stream>>>(x, w, xbits, winv);
    core_kernel<<<BB * HH + 128, 256, 0, stream>>>(xbits, winv, out);
}